// Round 1
// baseline (73.015 us; speedup 1.0000x reference)
//
#include <hip/hip_runtime.h>

#define VOCAB  100000
#define EMB    300
#define BATCH  16384
#define TOTAL  65536
#define NG     5
#define CHUNKS 75   // EMB/4 float4 chunks per row (1200 B, 16B-aligned)

// ---------------- Kernel A: fused gather + segment_sum ----------------
// One 64-lane wave per output segment. segment_ids is sorted, so the
// token range for segment `seg` is found by two binary searches.
// Lane i accumulates float4 chunk i; lanes 0..10 also accumulate chunk 64+i.
__global__ __launch_bounds__(64) void segsum_kernel(
    const float* __restrict__ W_in,
    const int*   __restrict__ flat_idx,
    const int*   __restrict__ seg_ids,
    float*       __restrict__ in_vec)
{
    const int seg  = blockIdx.x;
    const int lane = threadIdx.x;

    // lower_bound(seg)
    int lo = 0, hi = TOTAL;
    while (lo < hi) { int mid = (lo + hi) >> 1; if (seg_ids[mid] < seg) lo = mid + 1; else hi = mid; }
    const int start = lo;
    // lower_bound(seg+1)
    hi = TOTAL;
    while (lo < hi) { int mid = (lo + hi) >> 1; if (seg_ids[mid] < seg + 1) lo = mid + 1; else hi = mid; }
    const int end = lo;

    float4 acc0 = make_float4(0.f, 0.f, 0.f, 0.f);
    float4 acc1 = make_float4(0.f, 0.f, 0.f, 0.f);
    const bool extra = lane < (CHUNKS - 64);   // lanes 0..10

    for (int t = start; t < end; ++t) {
        const int idx = flat_idx[t];
        const float4* row = reinterpret_cast<const float4*>(W_in + (size_t)idx * EMB);
        const float4 v0 = row[lane];
        acc0.x += v0.x; acc0.y += v0.y; acc0.z += v0.z; acc0.w += v0.w;
        if (extra) {
            const float4 v1 = row[lane + 64];
            acc1.x += v1.x; acc1.y += v1.y; acc1.z += v1.z; acc1.w += v1.w;
        }
    }

    float4* dst = reinterpret_cast<float4*>(in_vec + (size_t)seg * EMB);
    dst[lane] = acc0;                 // empty segment -> zeros (segment_sum semantics)
    if (extra) dst[lane + 64] = acc1;
}

// ---------------- Kernel B: plain row gathers (out_vec + neg_vec) ----------------
// One thread per float4 chunk; rows 0..BATCH-1 -> out_vec, rest -> neg_vec.
__global__ __launch_bounds__(256) void gather_kernel(
    const float* __restrict__ W_out,
    const int*   __restrict__ out_idx,
    const int*   __restrict__ ng_idx,
    float*       __restrict__ out_vec,
    float*       __restrict__ neg_vec)
{
    const int gid = blockIdx.x * blockDim.x + threadIdx.x;
    const int total_chunks = (BATCH + BATCH * NG) * CHUNKS;  // 7,372,800
    if (gid >= total_chunks) return;

    const int row = gid / CHUNKS;    // magic-mul div by constant
    const int c   = gid % CHUNKS;

    int idx;
    float* dst;
    if (row < BATCH) {
        idx = out_idx[row];
        dst = out_vec + (size_t)row * EMB;
    } else {
        const int rr = row - BATCH;
        idx = ng_idx[rr];
        dst = neg_vec + (size_t)rr * EMB;
    }

    const float4* src = reinterpret_cast<const float4*>(W_out + (size_t)idx * EMB);
    reinterpret_cast<float4*>(dst)[c] = src[c];
}

extern "C" void kernel_launch(void* const* d_in, const int* in_sizes, int n_in,
                              void* d_out, int out_size, void* d_ws, size_t ws_size,
                              hipStream_t stream)
{
    const float* W_in   = (const float*)d_in[0];
    const float* W_out  = (const float*)d_in[1];
    const int*   flat   = (const int*)d_in[2];
    const int*   segids = (const int*)d_in[3];
    const int*   outidx = (const int*)d_in[4];
    const int*   ngidx  = (const int*)d_in[5];

    float* o       = (float*)d_out;
    float* in_vec  = o;                                  // [BATCH, EMB]
    float* out_vec = o + (size_t)BATCH * EMB;            // [BATCH, EMB]
    float* neg_vec = o + (size_t)2 * BATCH * EMB;        // [BATCH, NG, EMB]

    // Kernel A: one wave per segment
    segsum_kernel<<<BATCH, 64, 0, stream>>>(W_in, flat, segids, in_vec);

    // Kernel B: one thread per float4 chunk
    const int total_chunks = (BATCH + BATCH * NG) * CHUNKS;   // 7,372,800
    const int threads = 256;
    const int blocks  = (total_chunks + threads - 1) / threads;  // 28,800
    gather_kernel<<<blocks, threads, 0, stream>>>(W_out, outidx, ngidx, out_vec, neg_vec);
}